// Round 4
// baseline (352.185 us; speedup 1.0000x reference)
//
#include <hip/hip_runtime.h>
#include <math.h>

// Problem constants
#define LQ 1024
#define EQ 512
#define BQ 32
#define MQ 64

static constexpr int BCHUNK = LQ * EQ;   // 524288 floats per b-slice of d_out
// d_out overlay (per b-slice of 524288 floats), phase by phase:
//  stage1 (k_dft2):  Xpart[p][h][m][ri] p=0..3 at b*BCHUNK + p*65536        [0,262144)
//  k_redx2:          SPLITX bf16 arrays (see sx_ptr) in slices z=0..11 at
//                    [z][262144, 524288)  (disjoint from all Xpart)
//  stage2 (k_modes4): O_final[c][i] at b*BCHUNK + c*512 + i                 [0,65536)
//                    (Xpart dead by then; reads SPLITX + W only)
//  stage3 (k_inv2):  y[l][i] overwrites slice (reads only own cols of O first)

typedef short short8 __attribute__((ext_vector_type(8)));
typedef float f32x4 __attribute__((ext_vector_type(4)));

union FragI { int i[4]; int4 v; short8 s; };

// SPLITX: 6 bf16 arrays [m(64)][b(32)][h(512)], arr: 0=xrHi 1=xrLo 2=xiHi
// 3=xiLo 4=nxiHi 5=nxiLo. Flat bf16 index G = arr*2^20 + (m*32+b)*512 + h,
// mapped into 1MB-float zones at slice z = G>>19, offset 262144 floats.
__device__ inline char* sx_ptr(float* dout, int arr, int m, int b, int h) {
    unsigned G = ((unsigned)arr << 20) + (((unsigned)(m * 32 + b)) << 9) + (unsigned)h;
    unsigned z = G >> 19, w = G & 524287u;
    return (char*)(dout + (size_t)z * BCHUNK + 262144) + (size_t)w * 2;
}

// split two fp32 into packed bf16 pairs (truncation; lo captures the residual)
__device__ inline void split2(float a, float b, unsigned& hi, unsigned& lo) {
    unsigned ua = __float_as_uint(a), ub = __float_as_uint(b);
    unsigned ha = ua & 0xFFFF0000u, hb = ub & 0xFFFF0000u;
    hi = (ua >> 16) | hb;
    float la = a - __uint_as_float(ha);
    float lb = b - __uint_as_float(hb);
    lo = (__float_as_uint(la) >> 16) | (__float_as_uint(lb) & 0xFFFF0000u);
}

// ---------------- kernel 0: trig tables ----------------
__global__ __launch_bounds__(256) void k_trig(float* __restrict__ T1,
                                              float* __restrict__ Bas) {
    int idx = blockIdx.x * 256 + threadIdx.x;   // 0..65535 = l*64+m
    int l = idx >> 6, m = idx & 63;
    int tt = (l * m) & (LQ - 1);
    float ang = (float)tt * 6.135923151542565e-03f;  // 2*pi/1024
    float s, c;
    sincosf(ang, &s, &c);
    T1[idx * 2 + 0] = c;
    T1[idx * 2 + 1] = -s;
    float coef = (m == 0 ? 1.0f : 2.0f) * (1.0f / (float)LQ);
    Bas[l * 128 + 2 * m + 0] = coef * c;
    Bas[l * 128 + 2 * m + 1] = (m == 0) ? 0.0f : (-2.0f / (float)LQ) * s;
}

// ---------------- kernel 1: truncated DFT (l-split x4) ----------------
__global__ __launch_bounds__(256) void k_dft2(const float* __restrict__ q,
                                              const float* __restrict__ T1,
                                              float* __restrict__ dout) {
    __shared__ float qs[64 * 64];
    __shared__ float ts[64 * 128];
    const int t  = threadIdx.x;
    const int blk = blockIdx.x;
    const int b  = blk >> 5;
    const int h0 = ((blk >> 2) & 7) << 6;
    const int p  = blk & 3;
    const int hh = t & 31;
    const int g  = t >> 5;
    float accr[2][8] = {};
    float acci[2][8] = {};
    const float* qb = q + (size_t)b * (LQ * EQ) + h0;

    for (int lt = 0; lt < 4; ++lt) {
        const int l0 = p * 256 + (lt << 6);
        __syncthreads();
#pragma unroll
        for (int k = 0; k < 16; ++k) {
            int idx = k * 256 + t;
            int lp = idx >> 6, hp = idx & 63;
            qs[idx] = qb[(size_t)(l0 + lp) * EQ + hp];
        }
#pragma unroll
        for (int k = 0; k < 32; ++k) {
            int idx = k * 256 + t;
            ts[idx] = T1[l0 * 128 + idx];
        }
        __syncthreads();
#pragma unroll 4
        for (int lp = 0; lp < 64; ++lp) {
            float2 qq = *(const float2*)&qs[lp * 64 + 2 * hh];
            const float4* tr = (const float4*)&ts[lp * 128 + g * 16];
#pragma unroll
            for (int j = 0; j < 4; ++j) {
                float4 tv = tr[j];
                accr[0][2 * j]     += qq.x * tv.x;
                acci[0][2 * j]     += qq.x * tv.y;
                accr[0][2 * j + 1] += qq.x * tv.z;
                acci[0][2 * j + 1] += qq.x * tv.w;
                accr[1][2 * j]     += qq.y * tv.x;
                acci[1][2 * j]     += qq.y * tv.y;
                accr[1][2 * j + 1] += qq.y * tv.z;
                acci[1][2 * j + 1] += qq.y * tv.w;
            }
        }
    }
    float* xb = dout + (size_t)b * BCHUNK + (size_t)p * 65536;
#pragma unroll
    for (int hp = 0; hp < 2; ++hp) {
        int h = h0 + 2 * hh + hp;
#pragma unroll
        for (int mm = 0; mm < 8; ++mm) {
            int m = g * 8 + mm;
            float2 v = make_float2(accr[hp][mm], acci[hp][mm]);
            *(float2*)&xb[(size_t)(h * 64 + m) * 2] = v;
        }
    }
}

// ---------------- kernel 1b: sum partials, transpose, split to bf16 hi/lo ----
// grid 256 = b(32) x ht(8: 64 h). block 256.
__global__ __launch_bounds__(256) void k_redx2(float* __restrict__ dout) {
    __shared__ float Lr[64][65];   // [m][h']
    __shared__ float Li[64][65];
    const int t  = threadIdx.x;
    const int b  = blockIdx.x >> 3;
    const int h0 = (blockIdx.x & 7) << 6;
    const float* base = dout + (size_t)b * BCHUNK;
    // pass 1: sum 4 l-partials, write transposed fp32 to LDS
#pragma unroll
    for (int r = 0; r < 16; ++r) {
        int e = r * 256 + t;                 // 4096 = 64h' x 64m
        int hp = e >> 6, m = e & 63;
        const float* src = base + (size_t)(h0 + hp) * 128 + m * 2;
        float2 s = *(const float2*)(src);
        float2 v1 = *(const float2*)(src + 65536);
        float2 v2 = *(const float2*)(src + 2 * 65536);
        float2 v3 = *(const float2*)(src + 3 * 65536);
        s.x = (s.x + v1.x) + (v2.x + v3.x);
        s.y = (s.y + v1.y) + (v2.y + v3.y);
        Lr[m][hp] = s.x;
        Li[m][hp] = s.y;
    }
    __syncthreads();
    // pass 2: per (m, 8-h octet): split into 6 bf16 arrays [m][b][h]
#pragma unroll
    for (int r = 0; r < 2; ++r) {
        int o = r * 256 + t;                 // 512 = 64m x 8 octets
        int m = o >> 3, ho = o & 7;
        float xr[8], xi[8];
#pragma unroll
        for (int j = 0; j < 8; ++j) {
            xr[j] = Lr[m][ho * 8 + j];
            xi[j] = Li[m][ho * 8 + j];
        }
        unsigned rh[4], rl[4], ih[4], il[4], nh[4], nl[4];
#pragma unroll
        for (int k = 0; k < 4; ++k) {
            split2(xr[2 * k], xr[2 * k + 1], rh[k], rl[k]);
            split2(xi[2 * k], xi[2 * k + 1], ih[k], il[k]);
            nh[k] = ih[k] ^ 0x80008000u;
            nl[k] = il[k] ^ 0x80008000u;
        }
        int h = h0 + ho * 8;
        *(int4*)sx_ptr(dout, 0, m, b, h) = make_int4(rh[0], rh[1], rh[2], rh[3]);
        *(int4*)sx_ptr(dout, 1, m, b, h) = make_int4(rl[0], rl[1], rl[2], rl[3]);
        *(int4*)sx_ptr(dout, 2, m, b, h) = make_int4(ih[0], ih[1], ih[2], ih[3]);
        *(int4*)sx_ptr(dout, 3, m, b, h) = make_int4(il[0], il[1], il[2], il[3]);
        *(int4*)sx_ptr(dout, 4, m, b, h) = make_int4(nh[0], nh[1], nh[2], nh[3]);
        *(int4*)sx_ptr(dout, 5, m, b, h) = make_int4(nl[0], nl[1], nl[2], nl[3]);
    }
}

// ---------------- kernel 2: per-mode complex GEMM via split-bf16 MFMA -------
// Per mode m: O[i,b] = sum_h W[h,i,m]*x[b,h,m] (complex), M=i N=b K=h.
// grid 128 = mc(4: 16 m) x it(32: 16 i). block 512 = 8 waves; wave handles 2 m.
// A (W): 8 strided scalar fp32 loads/lane, split to bf16 hi/lo inline.
// B (x): SPLITX dwordx4 loads. No LDS, no barriers.
__global__ __launch_bounds__(512) void k_modes4(const float* __restrict__ wreal,
                                                const float* __restrict__ wimag,
                                                float* __restrict__ dout) {
    const int t    = threadIdx.x;
    const int wave = t >> 6;
    const int lane = t & 63;
    const int mc   = blockIdx.x >> 5;
    const int it   = blockIdx.x & 31;
    const int m0   = mc * 16 + wave * 2;
    const int i0   = it * 16;
    const int col  = lane & 15;          // A-row index (i) / B-col index (b)
    const int kg   = lane >> 4;          // k-group: k = kg*8 + j
    const int iA   = i0 + col;

    f32x4 zero4 = {0.f, 0.f, 0.f, 0.f};
    f32x4 acc[2][2][2];                  // [mi][ri][nt]
#pragma unroll
    for (int a = 0; a < 2; ++a)
#pragma unroll
        for (int bq = 0; bq < 2; ++bq)
#pragma unroll
            for (int c = 0; c < 2; ++c) acc[a][bq][c] = zero4;

    // W base pointers: element (h)*32768 + iA*64 + m
    const float* wbase[2][2];
#pragma unroll
    for (int mi = 0; mi < 2; ++mi) {
        wbase[mi][0] = wreal + (size_t)(kg * 8) * 32768 + iA * 64 + (m0 + mi);
        wbase[mi][1] = wimag + (size_t)(kg * 8) * 32768 + iA * 64 + (m0 + mi);
    }
    // SPLITX base (arr=0, mi=0, nt=0, h = kg*8); other offsets are constants:
    // +arr*4MB, +mi*32768B, +nt*16384B, +kk*64B
    const char* xp0 = sx_ptr(dout, 0, m0, col, kg * 8);

    for (int kk = 0; kk < 16; ++kk) {
#pragma unroll
        for (int mi = 0; mi < 2; ++mi) {
            // ---- A fragments: W hi/lo for parts r,i ----
            short8 aW[2][2];             // [part][prec]
#pragma unroll
            for (int part = 0; part < 2; ++part) {
                float v[8];
#pragma unroll
                for (int j = 0; j < 8; ++j)
                    v[j] = wbase[mi][part][(size_t)(kk * 32 + j) * 32768];
                FragI hiF, loF;
#pragma unroll
                for (int k = 0; k < 4; ++k) {
                    unsigned h, l;
                    split2(v[2 * k], v[2 * k + 1], h, l);
                    hiF.i[k] = (int)h;
                    loF.i[k] = (int)l;
                }
                aW[part][0] = hiF.s;
                aW[part][1] = loF.s;
            }
            // ---- B fragments: SPLITX arrays 0..5, nt 0..1 ----
            short8 bX[6][2];
            const char* xp = xp0 + (size_t)mi * 32768 + (size_t)kk * 64;
#pragma unroll
            for (int arr = 0; arr < 6; ++arr)
#pragma unroll
                for (int nt = 0; nt < 2; ++nt) {
                    FragI f;
                    f.v = *(const int4*)(xp + (size_t)arr * 4194304 +
                                         (size_t)nt * 16384);
                    bX[arr][nt] = f.s;
                }
            // ---- MFMA: 24 per mi ----
#define MM(A, B, C) C = __builtin_amdgcn_mfma_f32_16x16x32_bf16(A, B, C, 0, 0, 0)
#pragma unroll
            for (int nt = 0; nt < 2; ++nt) {
                // out_r = WrHi*xrHi + WrHi*xrLo + WrLo*xrHi
                //       + WiHi*nxiHi + WiHi*nxiLo + WiLo*nxiHi
                MM(aW[0][0], bX[0][nt], acc[mi][0][nt]);
                MM(aW[0][0], bX[1][nt], acc[mi][0][nt]);
                MM(aW[0][1], bX[0][nt], acc[mi][0][nt]);
                MM(aW[1][0], bX[4][nt], acc[mi][0][nt]);
                MM(aW[1][0], bX[5][nt], acc[mi][0][nt]);
                MM(aW[1][1], bX[4][nt], acc[mi][0][nt]);
                // out_i = WrHi*xiHi + WrHi*xiLo + WrLo*xiHi
                //       + WiHi*xrHi + WiHi*xrLo + WiLo*xrHi
                MM(aW[0][0], bX[2][nt], acc[mi][1][nt]);
                MM(aW[0][0], bX[3][nt], acc[mi][1][nt]);
                MM(aW[0][1], bX[2][nt], acc[mi][1][nt]);
                MM(aW[1][0], bX[0][nt], acc[mi][1][nt]);
                MM(aW[1][0], bX[1][nt], acc[mi][1][nt]);
                MM(aW[1][1], bX[0][nt], acc[mi][1][nt]);
            }
#undef MM
        }
    }
    // epilogue: D row = i (lane>>4)*4+reg, col = b (lane&15)
#pragma unroll
    for (int mi = 0; mi < 2; ++mi)
#pragma unroll
        for (int part = 0; part < 2; ++part)
#pragma unroll
            for (int nt = 0; nt < 2; ++nt) {
                int bb = nt * 16 + col;
                int iSt = i0 + (lane >> 4) * 4;
                int c = 2 * (m0 + mi) + part;
                f32x4 vv = acc[mi][part][nt];
                float4 o = make_float4(vv.x, vv.y, vv.z, vv.w);
                *(float4*)&dout[(size_t)bb * BCHUNK + (size_t)c * EQ + iSt] = o;
            }
}

// ---------------- kernel 3: truncated irfft (i-split x16) ----------------
__global__ __launch_bounds__(256) void k_inv2(const float* __restrict__ Bas,
                                              float* __restrict__ dout) {
    __shared__ float Os[128 * 32];
    __shared__ float Bs[64 * 132];
    const int t  = threadIdx.x;
    const int b  = blockIdx.x >> 4;
    const int i0 = (blockIdx.x & 15) << 5;
    float* yb = dout + (size_t)b * BCHUNK;
#pragma unroll
    for (int k = 0; k < 16; ++k) {
        int e = k * 256 + t;
        int c = e >> 5, ii = e & 31;
        Os[e] = yb[(size_t)c * EQ + i0 + ii];
    }
    __syncthreads();
    const int lg = t >> 3, ti2 = t & 7;
    for (int lt = 0; lt < 16; ++lt) {
        const int l0 = lt << 6;
        if (lt) __syncthreads();
#pragma unroll
        for (int k = 0; k < 32; ++k) {
            int e = k * 256 + t;
            int lp = e >> 7, c = e & 127;
            Bs[lp * 132 + c] = Bas[(size_t)(l0 + lp) * 128 + c];
        }
        __syncthreads();
        float4 acc[2] = {};
#pragma unroll 4
        for (int c = 0; c < 128; ++c) {
            float4 ov = *(const float4*)&Os[c * 32 + ti2 * 4];
#pragma unroll
            for (int j = 0; j < 2; ++j) {
                float bv = Bs[(lg * 2 + j) * 132 + c];
                acc[j].x += bv * ov.x;
                acc[j].y += bv * ov.y;
                acc[j].z += bv * ov.z;
                acc[j].w += bv * ov.w;
            }
        }
#pragma unroll
        for (int j = 0; j < 2; ++j) {
            int l = l0 + lg * 2 + j;
            *(float4*)&yb[(size_t)l * EQ + i0 + ti2 * 4] = acc[j];
        }
    }
}

extern "C" void kernel_launch(void* const* d_in, const int* in_sizes, int n_in,
                              void* d_out, int out_size, void* d_ws, size_t ws_size,
                              hipStream_t stream) {
    const float* q  = (const float*)d_in[0];
    const float* wr = (const float*)d_in[1];
    const float* wi = (const float*)d_in[2];
    float* out = (float*)d_out;
    float* T1  = (float*)d_ws;          // 131072 floats
    float* Bas = T1 + 131072;           // 131072 floats  (1 MB of ws total)

    hipLaunchKernelGGL(k_trig,   dim3(256),  dim3(256), 0, stream, T1, Bas);
    hipLaunchKernelGGL(k_dft2,   dim3(1024), dim3(256), 0, stream, q, T1, out);
    hipLaunchKernelGGL(k_redx2,  dim3(256),  dim3(256), 0, stream, out);
    hipLaunchKernelGGL(k_modes4, dim3(128),  dim3(512), 0, stream, wr, wi, out);
    hipLaunchKernelGGL(k_inv2,   dim3(512),  dim3(256), 0, stream, Bas, out);
}

// Round 5
// 236.181 us; speedup vs baseline: 1.4912x; 1.4912x over previous
//
#include <hip/hip_runtime.h>
#include <math.h>

// Problem constants
#define LQ 1024
#define EQ 512
#define BQ 32
#define MQ 64

static constexpr int BCHUNK = LQ * EQ;   // 524288 floats per b-slice of d_out
// d_out overlay (per b-slice of 524288 floats), phase by phase:
//  stage1 (k_dft2):  Xpart[p][h][m][ri] p=0..3 at b*BCHUNK + p*65536        [0,262144)
//  k_redx2:          SPLITX bf16 arrays (see sx_ptr) in slices z=0..11 at
//                    [z][262144, 524288)  (disjoint from all Xpart)
//  stage2 (k_modes5): Opart[hs][c][i] hs=0,1 at b*BCHUNK + (1+hs)*65536     [65536,196608)
//  k_osum:           O_final[c][i] at b*BCHUNK + c*512 + i                  [0,65536)
//  stage3 (k_inv2):  y[l][i] overwrites slice (reads only own cols of O first)

typedef short short8 __attribute__((ext_vector_type(8)));
typedef float f32x4 __attribute__((ext_vector_type(4)));

union FragI { int i[4]; int4 v; short8 s; };

// SPLITX: 6 bf16 arrays [m(64)][b(32)][h(512)], arr: 0=xrHi 1=xrLo 2=xiHi
// 3=xiLo 4=nxiHi 5=nxiLo. Flat bf16 index G = arr*2^20 + (m*32+b)*512 + h,
// mapped into 1MB-float zones at slice z = G>>19, offset 262144 floats.
__device__ inline char* sx_ptr(float* dout, int arr, int m, int b, int h) {
    unsigned G = ((unsigned)arr << 20) + (((unsigned)(m * 32 + b)) << 9) + (unsigned)h;
    unsigned z = G >> 19, w = G & 524287u;
    return (char*)(dout + (size_t)z * BCHUNK + 262144) + (size_t)w * 2;
}

// split two fp32 into packed bf16 pairs (truncation; lo captures the residual)
__device__ inline void split2(float a, float b, unsigned& hi, unsigned& lo) {
    unsigned ua = __float_as_uint(a), ub = __float_as_uint(b);
    unsigned ha = ua & 0xFFFF0000u, hb = ub & 0xFFFF0000u;
    hi = (ua >> 16) | hb;
    float la = a - __uint_as_float(ha);
    float lb = b - __uint_as_float(hb);
    lo = (__float_as_uint(la) >> 16) | (__float_as_uint(lb) & 0xFFFF0000u);
}

// ---------------- kernel 0: trig tables ----------------
__global__ __launch_bounds__(256) void k_trig(float* __restrict__ T1,
                                              float* __restrict__ Bas) {
    int idx = blockIdx.x * 256 + threadIdx.x;   // 0..65535 = l*64+m
    int l = idx >> 6, m = idx & 63;
    int tt = (l * m) & (LQ - 1);
    float ang = (float)tt * 6.135923151542565e-03f;  // 2*pi/1024
    float s, c;
    sincosf(ang, &s, &c);
    T1[idx * 2 + 0] = c;
    T1[idx * 2 + 1] = -s;
    float coef = (m == 0 ? 1.0f : 2.0f) * (1.0f / (float)LQ);
    Bas[l * 128 + 2 * m + 0] = coef * c;
    Bas[l * 128 + 2 * m + 1] = (m == 0) ? 0.0f : (-2.0f / (float)LQ) * s;
}

// ---------------- kernel 1: truncated DFT (l-split x4) ----------------
__global__ __launch_bounds__(256) void k_dft2(const float* __restrict__ q,
                                              const float* __restrict__ T1,
                                              float* __restrict__ dout) {
    __shared__ float qs[64 * 64];
    __shared__ float ts[64 * 128];
    const int t  = threadIdx.x;
    const int blk = blockIdx.x;
    const int b  = blk >> 5;
    const int h0 = ((blk >> 2) & 7) << 6;
    const int p  = blk & 3;
    const int hh = t & 31;
    const int g  = t >> 5;
    float accr[2][8] = {};
    float acci[2][8] = {};
    const float* qb = q + (size_t)b * (LQ * EQ) + h0;

    for (int lt = 0; lt < 4; ++lt) {
        const int l0 = p * 256 + (lt << 6);
        __syncthreads();
#pragma unroll
        for (int k = 0; k < 16; ++k) {
            int idx = k * 256 + t;
            int lp = idx >> 6, hp = idx & 63;
            qs[idx] = qb[(size_t)(l0 + lp) * EQ + hp];
        }
#pragma unroll
        for (int k = 0; k < 32; ++k) {
            int idx = k * 256 + t;
            ts[idx] = T1[l0 * 128 + idx];
        }
        __syncthreads();
#pragma unroll 4
        for (int lp = 0; lp < 64; ++lp) {
            float2 qq = *(const float2*)&qs[lp * 64 + 2 * hh];
            const float4* tr = (const float4*)&ts[lp * 128 + g * 16];
#pragma unroll
            for (int j = 0; j < 4; ++j) {
                float4 tv = tr[j];
                accr[0][2 * j]     += qq.x * tv.x;
                acci[0][2 * j]     += qq.x * tv.y;
                accr[0][2 * j + 1] += qq.x * tv.z;
                acci[0][2 * j + 1] += qq.x * tv.w;
                accr[1][2 * j]     += qq.y * tv.x;
                acci[1][2 * j]     += qq.y * tv.y;
                accr[1][2 * j + 1] += qq.y * tv.z;
                acci[1][2 * j + 1] += qq.y * tv.w;
            }
        }
    }
    float* xb = dout + (size_t)b * BCHUNK + (size_t)p * 65536;
#pragma unroll
    for (int hp = 0; hp < 2; ++hp) {
        int h = h0 + 2 * hh + hp;
#pragma unroll
        for (int mm = 0; mm < 8; ++mm) {
            int m = g * 8 + mm;
            float2 v = make_float2(accr[hp][mm], acci[hp][mm]);
            *(float2*)&xb[(size_t)(h * 64 + m) * 2] = v;
        }
    }
}

// ---------------- kernel 1b: sum partials, transpose, split to bf16 hi/lo ----
// grid 256 = b(32) x ht(8: 64 h). block 256.
__global__ __launch_bounds__(256) void k_redx2(float* __restrict__ dout) {
    __shared__ float Lr[64][65];   // [m][h']
    __shared__ float Li[64][65];
    const int t  = threadIdx.x;
    const int b  = blockIdx.x >> 3;
    const int h0 = (blockIdx.x & 7) << 6;
    const float* base = dout + (size_t)b * BCHUNK;
#pragma unroll
    for (int r = 0; r < 16; ++r) {
        int e = r * 256 + t;                 // 4096 = 64h' x 64m
        int hp = e >> 6, m = e & 63;
        const float* src = base + (size_t)(h0 + hp) * 128 + m * 2;
        float2 s = *(const float2*)(src);
        float2 v1 = *(const float2*)(src + 65536);
        float2 v2 = *(const float2*)(src + 2 * 65536);
        float2 v3 = *(const float2*)(src + 3 * 65536);
        s.x = (s.x + v1.x) + (v2.x + v3.x);
        s.y = (s.y + v1.y) + (v2.y + v3.y);
        Lr[m][hp] = s.x;
        Li[m][hp] = s.y;
    }
    __syncthreads();
#pragma unroll
    for (int r = 0; r < 2; ++r) {
        int o = r * 256 + t;                 // 512 = 64m x 8 octets
        int m = o >> 3, ho = o & 7;
        float xr[8], xi[8];
#pragma unroll
        for (int j = 0; j < 8; ++j) {
            xr[j] = Lr[m][ho * 8 + j];
            xi[j] = Li[m][ho * 8 + j];
        }
        unsigned rh[4], rl[4], ih[4], il[4], nh[4], nl[4];
#pragma unroll
        for (int k = 0; k < 4; ++k) {
            split2(xr[2 * k], xr[2 * k + 1], rh[k], rl[k]);
            split2(xi[2 * k], xi[2 * k + 1], ih[k], il[k]);
            nh[k] = ih[k] ^ 0x80008000u;
            nl[k] = il[k] ^ 0x80008000u;
        }
        int h = h0 + ho * 8;
        *(int4*)sx_ptr(dout, 0, m, b, h) = make_int4(rh[0], rh[1], rh[2], rh[3]);
        *(int4*)sx_ptr(dout, 1, m, b, h) = make_int4(rl[0], rl[1], rl[2], rl[3]);
        *(int4*)sx_ptr(dout, 2, m, b, h) = make_int4(ih[0], ih[1], ih[2], ih[3]);
        *(int4*)sx_ptr(dout, 3, m, b, h) = make_int4(il[0], il[1], il[2], il[3]);
        *(int4*)sx_ptr(dout, 4, m, b, h) = make_int4(nh[0], nh[1], nh[2], nh[3]);
        *(int4*)sx_ptr(dout, 5, m, b, h) = make_int4(nl[0], nl[1], nl[2], nl[3]);
    }
}

// ---------------- kernel 2: per-mode complex GEMM, v5 (LDS-staged W) -------
// Opart[hs][b][2m+ri][i] = sum_{h in hs half} X[b][h][m] * W[h][i][m]
// grid 256 = hs(2) x mc(4: 16 m) x it(32: 16 i). block 512 = 8 waves.
// Wave w owns modes {m0+2w, m0+2w+1}, both b-halves (nt), all 16 i rows.
// W staged coalesced (full 64B lines over m) into LDS [part][h][i][pad18],
// register-double-buffered so the HBM stream pipelines under compute.
// A-frags: 8x ds_read_b32 + split2 (identical numerics to round-4 verified).
// B-frags: SPLITX dwordx4 (L2-resident).
__global__ __launch_bounds__(512) void k_modes5(const float* __restrict__ wreal,
                                                const float* __restrict__ wimag,
                                                float* __restrict__ dout) {
    __shared__ float Wlds[2 * 32 * 16 * 18];   // 73728 B
    const int t    = threadIdx.x;
    const int wave = t >> 6;
    const int lane = t & 63;
    const int blk  = blockIdx.x;
    const int hs   = blk >> 7;
    const int mc   = (blk >> 5) & 3;
    const int it   = blk & 31;
    const int i0   = it * 16;
    const int m0   = mc * 16;
    const int col  = lane & 15;          // A row (i) / B col (b)
    const int kg   = lane >> 4;          // k-group
    const int hbase = hs * 256;

    // SPLITX per-lane base: arr=0, m=m0+2w, b=col, h=hbase+kg*8. Offsets:
    // +arr*4194304B, +mi*32768B, +nt*16384B, +kk*64B (no slice-cross: m-pairs
    // never straddle m=32, +16384 bf16 stays in-slice for m'<=30).
    const char* xp0 = sx_ptr(dout, 0, m0 + 2 * wave, col, hbase + kg * 8);

    f32x4 zero4 = {0.f, 0.f, 0.f, 0.f};
    f32x4 acc[2][2][2];                  // [mi][part][nt]
#pragma unroll
    for (int a = 0; a < 2; ++a)
#pragma unroll
        for (int bq = 0; bq < 2; ++bq)
#pragma unroll
            for (int c = 0; c < 2; ++c) acc[a][bq][c] = zero4;

    float2 st[16];                       // staging regs (double-buffer)
#define LOADK(KK)                                                             \
    {                                                                         \
        int h0_ = hbase + (KK) * 32;                                          \
        _Pragma("unroll")                                                     \
        for (int r = 0; r < 16; ++r) {                                        \
            int e = r * 512 + t;                                              \
            int m2 = e & 7, ii = (e >> 3) & 15, hh = (e >> 7) & 31;           \
            const float* src = (e >> 12) ? wimag : wreal;                     \
            st[r] = *(const float2*)&src[(size_t)(h0_ + hh) * 32768 +         \
                                         (size_t)(i0 + ii) * 64 + m0 + 2 * m2]; \
        }                                                                     \
    }

    LOADK(0);
    for (int kk = 0; kk < 8; ++kk) {
        // drain staging regs into LDS
#pragma unroll
        for (int r = 0; r < 16; ++r) {
            int e = r * 512 + t;
            int m2 = e & 7, ii = (e >> 3) & 15, hh = (e >> 7) & 31;
            int part = e >> 12;
            *(float2*)&Wlds[(((part * 32 + hh) * 16) + ii) * 18 + 2 * m2] = st[r];
        }
        __syncthreads();
        if (kk < 7) LOADK(kk + 1);       // prefetch next chunk under compute
#pragma unroll
        for (int mi = 0; mi < 2; ++mi) {
            const int mloc = 2 * wave + mi;
            // ---- A fragments: W hi/lo for parts r,i (from LDS) ----
            short8 aW[2][2];             // [part][prec]
#pragma unroll
            for (int part = 0; part < 2; ++part) {
                float v[8];
#pragma unroll
                for (int j = 0; j < 8; ++j)
                    v[j] = Wlds[((part * 32 + kg * 8 + j) * 16 + col) * 18 + mloc];
                FragI hiF, loF;
#pragma unroll
                for (int k = 0; k < 4; ++k) {
                    unsigned h, l;
                    split2(v[2 * k], v[2 * k + 1], h, l);
                    hiF.i[k] = (int)h;
                    loF.i[k] = (int)l;
                }
                aW[part][0] = hiF.s;
                aW[part][1] = loF.s;
            }
            // ---- B fragments + MFMA ----
            const char* xpm = xp0 + (size_t)mi * 32768 + (size_t)kk * 64;
#define MM(A, B, C) C = __builtin_amdgcn_mfma_f32_16x16x32_bf16(A, B, C, 0, 0, 0)
#pragma unroll
            for (int nt = 0; nt < 2; ++nt) {
                short8 bX[6];
#pragma unroll
                for (int arr = 0; arr < 6; ++arr) {
                    FragI f;
                    f.v = *(const int4*)(xpm + (size_t)arr * 4194304 +
                                         (size_t)nt * 16384);
                    bX[arr] = f.s;
                }
                // out_r
                MM(aW[0][0], bX[0], acc[mi][0][nt]);
                MM(aW[0][0], bX[1], acc[mi][0][nt]);
                MM(aW[0][1], bX[0], acc[mi][0][nt]);
                MM(aW[1][0], bX[4], acc[mi][0][nt]);
                MM(aW[1][0], bX[5], acc[mi][0][nt]);
                MM(aW[1][1], bX[4], acc[mi][0][nt]);
                // out_i
                MM(aW[0][0], bX[2], acc[mi][1][nt]);
                MM(aW[0][0], bX[3], acc[mi][1][nt]);
                MM(aW[0][1], bX[2], acc[mi][1][nt]);
                MM(aW[1][0], bX[0], acc[mi][1][nt]);
                MM(aW[1][0], bX[1], acc[mi][1][nt]);
                MM(aW[1][1], bX[0], acc[mi][1][nt]);
            }
#undef MM
        }
        __syncthreads();
    }
#undef LOADK
    // epilogue: D row = i = i0 + kg*4 + reg (contig float4), col = b
#pragma unroll
    for (int mi = 0; mi < 2; ++mi)
#pragma unroll
        for (int part = 0; part < 2; ++part)
#pragma unroll
            for (int nt = 0; nt < 2; ++nt) {
                int bb = nt * 16 + col;
                int c = 2 * (m0 + 2 * wave + mi) + part;
                f32x4 vv = acc[mi][part][nt];
                float4 o = make_float4(vv.x, vv.y, vv.z, vv.w);
                *(float4*)&dout[(size_t)bb * BCHUNK + (size_t)(1 + hs) * 65536 +
                                (size_t)c * EQ + i0 + kg * 4] = o;
            }
}

// ---------------- kernel 2b: O_final = sum of 2 h-split partials ----------
__global__ __launch_bounds__(256) void k_osum(float* __restrict__ dout) {
    int idx = blockIdx.x * 256 + threadIdx.x;   // float4 index, 524288 total
    int b = idx >> 14;                          // 16384 float4 per b
    int r = idx & 16383;
    float* base = dout + (size_t)b * BCHUNK;
    float4 s0 = ((const float4*)(base + 65536))[r];
    float4 s1 = ((const float4*)(base + 2 * 65536))[r];
    float4 o;
    o.x = s0.x + s1.x;
    o.y = s0.y + s1.y;
    o.z = s0.z + s1.z;
    o.w = s0.w + s1.w;
    ((float4*)base)[r] = o;
}

// ---------------- kernel 3: truncated irfft (i-split x16) ----------------
__global__ __launch_bounds__(256) void k_inv2(const float* __restrict__ Bas,
                                              float* __restrict__ dout) {
    __shared__ float Os[128 * 32];
    __shared__ float Bs[64 * 132];
    const int t  = threadIdx.x;
    const int b  = blockIdx.x >> 4;
    const int i0 = (blockIdx.x & 15) << 5;
    float* yb = dout + (size_t)b * BCHUNK;
#pragma unroll
    for (int k = 0; k < 16; ++k) {
        int e = k * 256 + t;
        int c = e >> 5, ii = e & 31;
        Os[e] = yb[(size_t)c * EQ + i0 + ii];
    }
    __syncthreads();
    const int lg = t >> 3, ti2 = t & 7;
    for (int lt = 0; lt < 16; ++lt) {
        const int l0 = lt << 6;
        if (lt) __syncthreads();
#pragma unroll
        for (int k = 0; k < 32; ++k) {
            int e = k * 256 + t;
            int lp = e >> 7, c = e & 127;
            Bs[lp * 132 + c] = Bas[(size_t)(l0 + lp) * 128 + c];
        }
        __syncthreads();
        float4 acc[2] = {};
#pragma unroll 4
        for (int c = 0; c < 128; ++c) {
            float4 ov = *(const float4*)&Os[c * 32 + ti2 * 4];
#pragma unroll
            for (int j = 0; j < 2; ++j) {
                float bv = Bs[(lg * 2 + j) * 132 + c];
                acc[j].x += bv * ov.x;
                acc[j].y += bv * ov.y;
                acc[j].z += bv * ov.z;
                acc[j].w += bv * ov.w;
            }
        }
#pragma unroll
        for (int j = 0; j < 2; ++j) {
            int l = l0 + lg * 2 + j;
            *(float4*)&yb[(size_t)l * EQ + i0 + ti2 * 4] = acc[j];
        }
    }
}

extern "C" void kernel_launch(void* const* d_in, const int* in_sizes, int n_in,
                              void* d_out, int out_size, void* d_ws, size_t ws_size,
                              hipStream_t stream) {
    const float* q  = (const float*)d_in[0];
    const float* wr = (const float*)d_in[1];
    const float* wi = (const float*)d_in[2];
    float* out = (float*)d_out;
    float* T1  = (float*)d_ws;          // 131072 floats
    float* Bas = T1 + 131072;           // 131072 floats  (1 MB of ws total)

    hipLaunchKernelGGL(k_trig,   dim3(256),  dim3(256), 0, stream, T1, Bas);
    hipLaunchKernelGGL(k_dft2,   dim3(1024), dim3(256), 0, stream, q, T1, out);
    hipLaunchKernelGGL(k_redx2,  dim3(256),  dim3(256), 0, stream, out);
    hipLaunchKernelGGL(k_modes5, dim3(256),  dim3(512), 0, stream, wr, wi, out);
    hipLaunchKernelGGL(k_osum,   dim3(2048), dim3(256), 0, stream, out);
    hipLaunchKernelGGL(k_inv2,   dim3(512),  dim3(256), 0, stream, Bas, out);
}

// Round 6
// 177.809 us; speedup vs baseline: 1.9807x; 1.3283x over previous
//
#include <hip/hip_runtime.h>
#include <math.h>

// Problem constants
#define LQ 1024
#define EQ 512
#define BQ 32
#define MQ 64

static constexpr int BCHUNK = LQ * EQ;   // 524288 floats per b-slice of d_out
// d_out overlay (per b-slice of 524288 floats), phase by phase:
//  stage1 (k_dft2):  Xpart[p][h][m][ri] p=0..3 at b*BCHUNK + p*65536        [0,262144)
//  k_redx2:          SPLITX bf16 arrays (see sx_ptr) in slices z=0..11 at
//                    [z][262144, 524288)  (disjoint from all Xpart)
//  stage2 (k_modes5): Opart[hs][c][i] hs=0..3 at b*BCHUNK + hs*65536        [0,262144)
//                    (Xpart dead by then; reads SPLITX + W only)
//  stage3 (k_inv3):  y[l][i] overwrites slice. Each block reads ONLY its own
//                    i-columns of the 4 partials (flat residues mod 512 equal
//                    its own output columns -> cross-block WAR-safe), staged
//                    to LDS before any write.

typedef short short8 __attribute__((ext_vector_type(8)));
typedef float f32x4 __attribute__((ext_vector_type(4)));

union FragI { int i[4]; int4 v; short8 s; };

// SPLITX: 6 bf16 arrays, fragment-friendly layout [m(64)][hblk(16)][b(32)][hh(32)]
// arr: 0=xrHi 1=xrLo 2=xiHi 3=xiLo 4=nxiHi 5=nxiLo.
// Flat bf16 index G = arr*2^20 + m*16384 + (h/32)*1024 + b*32 + (h%32),
// mapped into 1MB-float zones: zone z = G>>19 lives at slice z offset 262144.
// A B-fragment wave-load (16 b x 4 kg x 16B) covers 1024 CONTIGUOUS bytes.
__device__ inline char* sx_ptr(float* dout, int arr, int m, int b, int h) {
    unsigned G = ((unsigned)arr << 20) + ((unsigned)m << 14) +
                 ((unsigned)(h >> 5) << 10) + ((unsigned)b << 5) + (unsigned)(h & 31);
    unsigned z = G >> 19, w = G & 524287u;
    return (char*)(dout + (size_t)z * BCHUNK + 262144) + (size_t)w * 2;
}

// split two fp32 into packed bf16 pairs (truncation; lo captures the residual)
__device__ inline void split2(float a, float b, unsigned& hi, unsigned& lo) {
    unsigned ua = __float_as_uint(a), ub = __float_as_uint(b);
    unsigned ha = ua & 0xFFFF0000u, hb = ub & 0xFFFF0000u;
    hi = (ua >> 16) | hb;
    float la = a - __uint_as_float(ha);
    float lb = b - __uint_as_float(hb);
    lo = (__float_as_uint(la) >> 16) | (__float_as_uint(lb) & 0xFFFF0000u);
}

// ---------------- kernel 0: trig tables ----------------
// T1[l][m][2] = (cos, -sin) for the forward DFT.
// BFhi/BFlo: irfft basis Bas[l][c] (c=2m -> coef*cos, c=2m+1 -> -2/L*sin,
// Im X0 ignored) pre-packed in MFMA A-fragment layout:
// u32 idx = lt*1024 + kb*256 + lane*4 + (m&3), lane = kg*16 + (l&15).
__global__ __launch_bounds__(256) void k_trig(float* __restrict__ T1,
                                              unsigned* __restrict__ BFhi,
                                              unsigned* __restrict__ BFlo) {
    int idx = blockIdx.x * 256 + threadIdx.x;   // 0..65535 = l*64+m
    int l = idx >> 6, m = idx & 63;
    int tt = (l * m) & (LQ - 1);
    float ang = (float)tt * 6.135923151542565e-03f;  // 2*pi/1024
    float s, c;
    sincosf(ang, &s, &c);
    T1[idx * 2 + 0] = c;
    T1[idx * 2 + 1] = -s;
    float coef = (m == 0 ? 1.0f : 2.0f) * (1.0f / (float)LQ);
    float b0 = coef * c;
    float b1 = (m == 0) ? 0.0f : (-2.0f / (float)LQ) * s;
    unsigned hi, lo;
    split2(b0, b1, hi, lo);
    int lt = l >> 4, kb = m >> 4, kg = (m & 15) >> 2;
    int lane = kg * 16 + (l & 15);
    int u = lt * 1024 + kb * 256 + lane * 4 + (m & 3);
    BFhi[u] = hi;
    BFlo[u] = lo;
}

// ---------------- kernel 1: truncated DFT (l-split x4) ----------------
__global__ __launch_bounds__(256) void k_dft2(const float* __restrict__ q,
                                              const float* __restrict__ T1,
                                              float* __restrict__ dout) {
    __shared__ float qs[64 * 64];
    __shared__ float ts[64 * 128];
    const int t  = threadIdx.x;
    const int blk = blockIdx.x;
    const int b  = blk >> 5;
    const int h0 = ((blk >> 2) & 7) << 6;
    const int p  = blk & 3;
    const int hh = t & 31;
    const int g  = t >> 5;
    float accr[2][8] = {};
    float acci[2][8] = {};
    const float* qb = q + (size_t)b * (LQ * EQ) + h0;

    for (int lt = 0; lt < 4; ++lt) {
        const int l0 = p * 256 + (lt << 6);
        __syncthreads();
#pragma unroll
        for (int k = 0; k < 16; ++k) {
            int idx = k * 256 + t;
            int lp = idx >> 6, hp = idx & 63;
            qs[idx] = qb[(size_t)(l0 + lp) * EQ + hp];
        }
#pragma unroll
        for (int k = 0; k < 32; ++k) {
            int idx = k * 256 + t;
            ts[idx] = T1[l0 * 128 + idx];
        }
        __syncthreads();
#pragma unroll 4
        for (int lp = 0; lp < 64; ++lp) {
            float2 qq = *(const float2*)&qs[lp * 64 + 2 * hh];
            const float4* tr = (const float4*)&ts[lp * 128 + g * 16];
#pragma unroll
            for (int j = 0; j < 4; ++j) {
                float4 tv = tr[j];
                accr[0][2 * j]     += qq.x * tv.x;
                acci[0][2 * j]     += qq.x * tv.y;
                accr[0][2 * j + 1] += qq.x * tv.z;
                acci[0][2 * j + 1] += qq.x * tv.w;
                accr[1][2 * j]     += qq.y * tv.x;
                acci[1][2 * j]     += qq.y * tv.y;
                accr[1][2 * j + 1] += qq.y * tv.z;
                acci[1][2 * j + 1] += qq.y * tv.w;
            }
        }
    }
    float* xb = dout + (size_t)b * BCHUNK + (size_t)p * 65536;
#pragma unroll
    for (int hp = 0; hp < 2; ++hp) {
        int h = h0 + 2 * hh + hp;
#pragma unroll
        for (int mm = 0; mm < 8; ++mm) {
            int m = g * 8 + mm;
            float2 v = make_float2(accr[hp][mm], acci[hp][mm]);
            *(float2*)&xb[(size_t)(h * 64 + m) * 2] = v;
        }
    }
}

// ---------------- kernel 1b: sum partials, transpose, split to bf16 hi/lo ----
// grid 256 = b(32) x ht(8: 64 h). block 256.
__global__ __launch_bounds__(256) void k_redx2(float* __restrict__ dout) {
    __shared__ float Lr[64][65];   // [m][h']
    __shared__ float Li[64][65];
    const int t  = threadIdx.x;
    const int b  = blockIdx.x >> 3;
    const int h0 = (blockIdx.x & 7) << 6;
    const float* base = dout + (size_t)b * BCHUNK;
#pragma unroll
    for (int r = 0; r < 16; ++r) {
        int e = r * 256 + t;                 // 4096 = 64h' x 64m
        int hp = e >> 6, m = e & 63;
        const float* src = base + (size_t)(h0 + hp) * 128 + m * 2;
        float2 s = *(const float2*)(src);
        float2 v1 = *(const float2*)(src + 65536);
        float2 v2 = *(const float2*)(src + 2 * 65536);
        float2 v3 = *(const float2*)(src + 3 * 65536);
        s.x = (s.x + v1.x) + (v2.x + v3.x);
        s.y = (s.y + v1.y) + (v2.y + v3.y);
        Lr[m][hp] = s.x;
        Li[m][hp] = s.y;
    }
    __syncthreads();
#pragma unroll
    for (int r = 0; r < 2; ++r) {
        int o = r * 256 + t;                 // 512 = 64m x 8 octets
        int m = o >> 3, ho = o & 7;
        float xr[8], xi[8];
#pragma unroll
        for (int j = 0; j < 8; ++j) {
            xr[j] = Lr[m][ho * 8 + j];
            xi[j] = Li[m][ho * 8 + j];
        }
        unsigned rh[4], rl[4], ih[4], il[4], nh[4], nl[4];
#pragma unroll
        for (int k = 0; k < 4; ++k) {
            split2(xr[2 * k], xr[2 * k + 1], rh[k], rl[k]);
            split2(xi[2 * k], xi[2 * k + 1], ih[k], il[k]);
            nh[k] = ih[k] ^ 0x80008000u;
            nl[k] = il[k] ^ 0x80008000u;
        }
        int h = h0 + ho * 8;
        *(int4*)sx_ptr(dout, 0, m, b, h) = make_int4(rh[0], rh[1], rh[2], rh[3]);
        *(int4*)sx_ptr(dout, 1, m, b, h) = make_int4(rl[0], rl[1], rl[2], rl[3]);
        *(int4*)sx_ptr(dout, 2, m, b, h) = make_int4(ih[0], ih[1], ih[2], ih[3]);
        *(int4*)sx_ptr(dout, 3, m, b, h) = make_int4(il[0], il[1], il[2], il[3]);
        *(int4*)sx_ptr(dout, 4, m, b, h) = make_int4(nh[0], nh[1], nh[2], nh[3]);
        *(int4*)sx_ptr(dout, 5, m, b, h) = make_int4(nl[0], nl[1], nl[2], nl[3]);
    }
}

// ---------------- kernel 2: per-mode complex GEMM, v6 ----------------
// Opart[hs][b][2m+ri][i] = sum_{h in hs quarter} X[b][h][m] * W[h][i][m]
// grid 512 = hs(4) x mc(4: 16 m) x it(32: 16 i). block 512 = 8 waves.
// 2 blocks/CU (72KB LDS) -> 16 waves/CU for latency hiding.
// W staged coalesced into LDS, register-double-buffered; A-frags built by
// 8x ds_read_b32 + split2. B-frags: SPLITX contiguous 1KB wave-loads.
__global__ __launch_bounds__(512) void k_modes5(const float* __restrict__ wreal,
                                                const float* __restrict__ wimag,
                                                float* __restrict__ dout) {
    __shared__ float Wlds[2 * 32 * 16 * 18];   // 73728 B
    const int t    = threadIdx.x;
    const int wave = t >> 6;
    const int lane = t & 63;
    const int blk  = blockIdx.x;
    const int hs   = blk >> 7;           // 0..3
    const int mc   = (blk >> 5) & 3;
    const int it   = blk & 31;
    const int i0   = it * 16;
    const int m0   = mc * 16;
    const int col  = lane & 15;          // A row (i) / B col (b)
    const int kg   = lane >> 4;          // k-group
    const int hbase = hs * 128;

    // per-lane SPLITX base: arr=0, m=m0+2w, b=col, h=hbase+kg*8.
    // offsets: +arr*4194304B (2-zone stride), +mi*32768B, +nt*1024B, +kk*2048B
    const char* xp0 = sx_ptr(dout, 0, m0 + 2 * wave, col, hbase + kg * 8);

    f32x4 zero4 = {0.f, 0.f, 0.f, 0.f};
    f32x4 acc[2][2][2];                  // [mi][part][nt]
#pragma unroll
    for (int a = 0; a < 2; ++a)
#pragma unroll
        for (int bq = 0; bq < 2; ++bq)
#pragma unroll
            for (int c = 0; c < 2; ++c) acc[a][bq][c] = zero4;

    float2 st[16];                       // staging regs (double-buffer)
#define LOADK(KK)                                                             \
    {                                                                         \
        int h0_ = hbase + (KK) * 32;                                          \
        _Pragma("unroll")                                                     \
        for (int r = 0; r < 16; ++r) {                                        \
            int e = r * 512 + t;                                              \
            int m2 = e & 7, ii = (e >> 3) & 15, hh = (e >> 7) & 31;           \
            const float* src = (e >> 12) ? wimag : wreal;                     \
            st[r] = *(const float2*)&src[(size_t)(h0_ + hh) * 32768 +         \
                                         (size_t)(i0 + ii) * 64 + m0 + 2 * m2]; \
        }                                                                     \
    }

    LOADK(0);
    for (int kk = 0; kk < 4; ++kk) {
        // drain staging regs into LDS
#pragma unroll
        for (int r = 0; r < 16; ++r) {
            int e = r * 512 + t;
            int m2 = e & 7, ii = (e >> 3) & 15, hh = (e >> 7) & 31;
            int part = e >> 12;
            *(float2*)&Wlds[(((part * 32 + hh) * 16) + ii) * 18 + 2 * m2] = st[r];
        }
        __syncthreads();
        if (kk < 3) LOADK(kk + 1);       // prefetch next chunk under compute
#pragma unroll
        for (int mi = 0; mi < 2; ++mi) {
            const int mloc = 2 * wave + mi;
            // ---- A fragments: W hi/lo for parts r,i (from LDS) ----
            short8 aW[2][2];             // [part][prec]
#pragma unroll
            for (int part = 0; part < 2; ++part) {
                float v[8];
#pragma unroll
                for (int j = 0; j < 8; ++j)
                    v[j] = Wlds[((part * 32 + kg * 8 + j) * 16 + col) * 18 + mloc];
                FragI hiF, loF;
#pragma unroll
                for (int k = 0; k < 4; ++k) {
                    unsigned h, l;
                    split2(v[2 * k], v[2 * k + 1], h, l);
                    hiF.i[k] = (int)h;
                    loF.i[k] = (int)l;
                }
                aW[part][0] = hiF.s;
                aW[part][1] = loF.s;
            }
            // ---- B fragments + MFMA ----
            const char* xpm = xp0 + (size_t)mi * 32768 + (size_t)kk * 2048;
#define MM(A, B, C) C = __builtin_amdgcn_mfma_f32_16x16x32_bf16(A, B, C, 0, 0, 0)
#pragma unroll
            for (int nt = 0; nt < 2; ++nt) {
                short8 bX[6];
#pragma unroll
                for (int arr = 0; arr < 6; ++arr) {
                    FragI f;
                    f.v = *(const int4*)(xpm + (size_t)arr * 4194304 +
                                         (size_t)nt * 1024);
                    bX[arr] = f.s;
                }
                // out_r
                MM(aW[0][0], bX[0], acc[mi][0][nt]);
                MM(aW[0][0], bX[1], acc[mi][0][nt]);
                MM(aW[0][1], bX[0], acc[mi][0][nt]);
                MM(aW[1][0], bX[4], acc[mi][0][nt]);
                MM(aW[1][0], bX[5], acc[mi][0][nt]);
                MM(aW[1][1], bX[4], acc[mi][0][nt]);
                // out_i
                MM(aW[0][0], bX[2], acc[mi][1][nt]);
                MM(aW[0][0], bX[3], acc[mi][1][nt]);
                MM(aW[0][1], bX[2], acc[mi][1][nt]);
                MM(aW[1][0], bX[0], acc[mi][1][nt]);
                MM(aW[1][0], bX[1], acc[mi][1][nt]);
                MM(aW[1][1], bX[0], acc[mi][1][nt]);
            }
#undef MM
        }
        __syncthreads();
    }
#undef LOADK
    // epilogue: D row = i = i0 + kg*4 + reg (contig float4), col = b
#pragma unroll
    for (int mi = 0; mi < 2; ++mi)
#pragma unroll
        for (int part = 0; part < 2; ++part)
#pragma unroll
            for (int nt = 0; nt < 2; ++nt) {
                int bb = nt * 16 + col;
                int c = 2 * (m0 + 2 * wave + mi) + part;
                f32x4 vv = acc[mi][part][nt];
                float4 o = make_float4(vv.x, vv.y, vv.z, vv.w);
                *(float4*)&dout[(size_t)bb * BCHUNK + (size_t)hs * 65536 +
                                (size_t)c * EQ + i0 + kg * 4] = o;
            }
}

// ---------------- kernel 3: truncated irfft via MFMA ----------------
// y[b][l][i] = sum_c Bas[l][c] * O[b][c][i];  O = sum of 4 Opart.
// grid 512 = b(32) x it(16: 32 i). block 256 = 4 waves; wave does 16 l-tiles.
// A = Bas bf16 hi/lo fragments from ws (L2-hot, 512KB).
// B = O columns summed + split to bf16 frags in LDS (own i-columns only ->
// cross-block WAR-safe; staged fully before any y-write).
__global__ __launch_bounds__(256) void k_inv3(const unsigned* __restrict__ BFhi,
                                              const unsigned* __restrict__ BFlo,
                                              float* __restrict__ dout) {
    __shared__ unsigned Bf[4096];   // [hilo(2)][nt(2)][kb(4)][lane(64)][4] 16KB
    const int t    = threadIdx.x;
    const int wave = t >> 6;
    const int lane = t & 63;
    const int b    = blockIdx.x >> 4;
    const int it   = blockIdx.x & 15;
    const int i0   = it * 32;
    float* base = dout + (size_t)b * BCHUNK;

    // ---- stage: sum 4 partials for own 32 i-columns, split to B-frags ----
#pragma unroll
    for (int r = 0; r < 8; ++r) {
        int idx = r * 256 + t;               // 2048 = 64 c-pairs x 32 i
        int il = idx & 31, cp = idx >> 5;
        int c0 = 2 * cp;
        const float* p0 = base + (size_t)c0 * EQ + i0 + il;
        float s0 = p0[0] + p0[65536] + p0[2 * 65536] + p0[3 * 65536];
        const float* p1 = p0 + EQ;
        float s1 = p1[0] + p1[65536] + p1[2 * 65536] + p1[3 * 65536];
        unsigned hi, lo;
        split2(s0, s1, hi, lo);
        int nt = il >> 4, i_loc = il & 15;
        int kb = c0 >> 5, kg = (c0 & 31) >> 3, jp = (c0 & 7) >> 1;
        int u = (nt * 4 + kb) * 256 + (kg * 16 + i_loc) * 4 + jp;
        Bf[u] = hi;
        Bf[2048 + u] = lo;
    }
    __syncthreads();
    // ---- hoist B-frags to registers (shared across all 16 l-tiles) ----
    FragI bh[2][4], bl[2][4];
#pragma unroll
    for (int nt = 0; nt < 2; ++nt)
#pragma unroll
        for (int kb = 0; kb < 4; ++kb) {
            bh[nt][kb].v = *(const int4*)&Bf[(nt * 4 + kb) * 256 + lane * 4];
            bl[nt][kb].v = *(const int4*)&Bf[2048 + (nt * 4 + kb) * 256 + lane * 4];
        }
    // ---- main: per l-tile load A-frags, 24 MFMA, store ----
#define MM(A, B, C) C = __builtin_amdgcn_mfma_f32_16x16x32_bf16(A, B, C, 0, 0, 0)
    for (int r = 0; r < 16; ++r) {
        int lt = wave + 4 * r;
        FragI ah[4], al[4];
#pragma unroll
        for (int kb = 0; kb < 4; ++kb) {
            ah[kb].v = *(const int4*)&BFhi[lt * 1024 + kb * 256 + lane * 4];
            al[kb].v = *(const int4*)&BFlo[lt * 1024 + kb * 256 + lane * 4];
        }
        f32x4 a0 = {0.f, 0.f, 0.f, 0.f}, a1 = {0.f, 0.f, 0.f, 0.f};
#pragma unroll
        for (int kb = 0; kb < 4; ++kb) {
            MM(ah[kb].s, bh[0][kb].s, a0);
            MM(ah[kb].s, bl[0][kb].s, a0);
            MM(al[kb].s, bh[0][kb].s, a0);
            MM(ah[kb].s, bh[1][kb].s, a1);
            MM(ah[kb].s, bl[1][kb].s, a1);
            MM(al[kb].s, bh[1][kb].s, a1);
        }
        int lrow = lt * 16 + (lane >> 4) * 4;
        int icol = i0 + (lane & 15);
#pragma unroll
        for (int j = 0; j < 4; ++j) {
            base[(size_t)(lrow + j) * EQ + icol]      = a0[j];
            base[(size_t)(lrow + j) * EQ + icol + 16] = a1[j];
        }
    }
#undef MM
}

extern "C" void kernel_launch(void* const* d_in, const int* in_sizes, int n_in,
                              void* d_out, int out_size, void* d_ws, size_t ws_size,
                              hipStream_t stream) {
    const float* q  = (const float*)d_in[0];
    const float* wr = (const float*)d_in[1];
    const float* wi = (const float*)d_in[2];
    float* out = (float*)d_out;
    float* T1  = (float*)d_ws;                  // floats [0, 131072)
    unsigned* BFhi = (unsigned*)(T1 + 131072);  // floats [131072, 196608)
    unsigned* BFlo = (unsigned*)(T1 + 196608);  // floats [196608, 262144)

    hipLaunchKernelGGL(k_trig,   dim3(256),  dim3(256), 0, stream, T1, BFhi, BFlo);
    hipLaunchKernelGGL(k_dft2,   dim3(1024), dim3(256), 0, stream, q, T1, out);
    hipLaunchKernelGGL(k_redx2,  dim3(256),  dim3(256), 0, stream, out);
    hipLaunchKernelGGL(k_modes5, dim3(512),  dim3(512), 0, stream, wr, wi, out);
    hipLaunchKernelGGL(k_inv3,   dim3(512),  dim3(256), 0, stream, BFhi, BFlo, out);
}

// Round 7
// 135.907 us; speedup vs baseline: 2.5914x; 1.3083x over previous
//
#include <hip/hip_runtime.h>
#include <math.h>

// Problem constants
#define LQ 1024
#define EQ 512
#define BQ 32
#define MQ 64

static constexpr int BCHUNK = LQ * EQ;   // 524288 floats per b-slice of d_out
// d_out overlay (per b-slice of 524288 floats), phase by phase:
//  k_trig:   Tm bf16 A-frags in slice0 floats [0, 131072)  (hi: [0,65536), lo: [65536,131072))
//  k_dft3:   reads q + Tm-frags; writes SPLITX bf16 arrays (sx_ptr) in slices
//            z=0..11 at [z][262144, 524288)  (disjoint from Tm-frag region)
//  k_modes5: Opart[hs][c][i] hs=0..3 at b*BCHUNK + hs*65536  [0,262144)
//            (overwrites Tm-frags -- dft3 already done; reads SPLITX + W only)
//  k_inv3:   y[l][i] overwrites slice. Each block reads ONLY its own i-columns
//            of the 4 partials (staged to LDS before any write -> WAR-safe).

typedef short short8 __attribute__((ext_vector_type(8)));
typedef float f32x4 __attribute__((ext_vector_type(4)));
typedef unsigned short ushort_t;

union FragI { int i[4]; int4 v; short8 s; };

// SPLITX: 6 bf16 arrays, fragment-friendly layout [m(64)][hblk(16)][b(32)][hh(32)]
// arr: 0=xrHi 1=xrLo 2=xiHi 3=xiLo 4=nxiHi 5=nxiLo.
// Flat bf16 index G = arr*2^20 + m*16384 + (h/32)*1024 + b*32 + (h%32),
// mapped into 1MB-float zones: zone z = G>>19 lives at slice z offset 262144.
__device__ inline char* sx_ptr(float* dout, int arr, int m, int b, int h) {
    unsigned G = ((unsigned)arr << 20) + ((unsigned)m << 14) +
                 ((unsigned)(h >> 5) << 10) + ((unsigned)b << 5) + (unsigned)(h & 31);
    unsigned z = G >> 19, w = G & 524287u;
    return (char*)(dout + (size_t)z * BCHUNK + 262144) + (size_t)w * 2;
}

// split two fp32 into packed bf16 pairs (truncation; lo captures the residual)
__device__ inline void split2(float a, float b, unsigned& hi, unsigned& lo) {
    unsigned ua = __float_as_uint(a), ub = __float_as_uint(b);
    unsigned ha = ua & 0xFFFF0000u, hb = ub & 0xFFFF0000u;
    hi = (ua >> 16) | hb;
    float la = a - __uint_as_float(ha);
    float lb = b - __uint_as_float(hb);
    lo = (__float_as_uint(la) >> 16) | (__float_as_uint(lb) & 0xFFFF0000u);
}

// single-value truncation split (same numerics as split2, one element)
__device__ inline void split1(float x, ushort_t& hi, ushort_t& lo) {
    unsigned u = __float_as_uint(x);
    hi = (ushort_t)(u >> 16);
    float r = x - __uint_as_float(u & 0xFFFF0000u);
    lo = (ushort_t)(__float_as_uint(r) >> 16);
}

// ---------------- kernel 0: trig tables ----------------
// BFhi/BFlo (ws): irfft basis Bas[l][c] (c=2m -> coef*cos, c=2m+1 -> -2/L*sin,
// Im X0 ignored) packed in MFMA A-frag layout (unchanged from round 6).
// THs/TLs (d_out slice0): forward-DFT matrix Tm[mc][l] (mc=2m: cos, 2m+1: -sin)
// as bf16 hi/lo A-fragments: bf16 idx = ((ks*8 + mt)*64 + lane)*8 + j,
// lane = kg*16 + (mc&15), ks=l>>5, kg=(l>>3)&3, j=l&7, mt=mc>>4.
__global__ __launch_bounds__(256) void k_trig(unsigned* __restrict__ BFhi,
                                              unsigned* __restrict__ BFlo,
                                              float* __restrict__ dout) {
    int idx = blockIdx.x * 256 + threadIdx.x;   // 0..65535 = l*64+m
    int l = idx >> 6, m = idx & 63;
    int tt = (l * m) & (LQ - 1);
    float ang = (float)tt * 6.135923151542565e-03f;  // 2*pi/1024
    float s, c;
    sincosf(ang, &s, &c);
    // irfft basis fragments (ws)
    float coef = (m == 0 ? 1.0f : 2.0f) * (1.0f / (float)LQ);
    float b0 = coef * c;
    float b1 = (m == 0) ? 0.0f : (-2.0f / (float)LQ) * s;
    unsigned hi, lo;
    split2(b0, b1, hi, lo);
    {
        int lt = l >> 4, kb = m >> 4, kgb = (m & 15) >> 2;
        int lane = kgb * 16 + (l & 15);
        int u = lt * 1024 + kb * 256 + lane * 4 + (m & 3);
        BFhi[u] = hi;
        BFlo[u] = lo;
    }
    // forward-DFT fragments (d_out slice0)
    ushort_t* THs = (ushort_t*)dout;
    ushort_t* TLs = (ushort_t*)(dout + 65536);
    int ks = l >> 5, kg = (l >> 3) & 3, j = l & 7;
    int mt = m >> 3;
    int lane0 = kg * 16 + 2 * (m & 7);          // row mc=2m
    ushort_t ch, cl, sh, sl;
    split1(c, ch, cl);                          // cos
    split1(-s, sh, sl);                         // -sin
    int u0 = ((ks * 8 + mt) * 64 + lane0) * 8 + j;
    THs[u0] = ch;  TLs[u0] = cl;
    THs[u0 + 8] = sh;  TLs[u0 + 8] = sl;        // row mc=2m+1 (lane0+1)
}

// ---------------- kernel 1: truncated DFT via MFMA, fused SPLITX output -----
// Per b: D[mc][h] = sum_l Tm[mc][l] * q[l][h]; M=mc(128), K=l(1024), N=h(512).
// grid 512 = b(32) x hg(16: 32 h). block 512 = 8 waves: a=wave&3 -> mc-tiles
// {2a,2a+1}; ht=wave>>2 -> h-tile. q staged per 64-l chunk into LDS (reg
// double-buffered); B-frags = q split2'd from LDS; A-frags = Tm dwordx4 (L2).
// Epilogue splits fp32 accumulators directly into the 6 SPLITX arrays.
__global__ __launch_bounds__(512) void k_dft3(const float* __restrict__ q,
                                              float* __restrict__ dout) {
    __shared__ float qs[64][34];
    const int t    = threadIdx.x;
    const int wave = t >> 6;
    const int lane = t & 63;
    const int a    = wave & 3;
    const int ht   = wave >> 2;
    const int b    = blockIdx.x >> 4;
    const int hg   = blockIdx.x & 15;
    const int hbase = hg * 32;
    const int col  = lane & 15;
    const int kg   = lane >> 4;
    const float* qb = q + (size_t)b * BCHUNK;
    const int4* TH4 = (const int4*)dout;
    const int4* TL4 = (const int4*)(dout + 65536);

    f32x4 acc[2] = {{0.f, 0.f, 0.f, 0.f}, {0.f, 0.f, 0.f, 0.f}};
    float2 st2[2];
#define LOADQ(CC)                                                             \
    {                                                                         \
        int l0_ = (CC) * 64;                                                  \
        _Pragma("unroll")                                                     \
        for (int r = 0; r < 2; ++r) {                                         \
            int e = r * 512 + t;                                              \
            int lp = e >> 4, hc = (e & 15) * 2;                               \
            st2[r] = *(const float2*)&qb[(size_t)(l0_ + lp) * EQ + hbase + hc]; \
        }                                                                     \
    }

    LOADQ(0);
#define MM(A, B, C) C = __builtin_amdgcn_mfma_f32_16x16x32_bf16(A, B, C, 0, 0, 0)
    for (int cchunk = 0; cchunk < 16; ++cchunk) {
#pragma unroll
        for (int r = 0; r < 2; ++r) {           // drain staging regs -> LDS
            int e = r * 512 + t;
            int lp = e >> 4, hc = (e & 15) * 2;
            *(float2*)&qs[lp][hc] = st2[r];
        }
        __syncthreads();
        if (cchunk < 15) LOADQ(cchunk + 1);     // prefetch next chunk
#pragma unroll
        for (int ksl = 0; ksl < 2; ++ksl) {
            const int ks = cchunk * 2 + ksl;
            // B-frag: q[l][h] hi/lo
            float v[8];
#pragma unroll
            for (int j = 0; j < 8; ++j)
                v[j] = qs[ksl * 32 + kg * 8 + j][ht * 16 + col];
            FragI bhiF, bloF;
#pragma unroll
            for (int k = 0; k < 4; ++k) {
                unsigned h_, l_;
                split2(v[2 * k], v[2 * k + 1], h_, l_);
                bhiF.i[k] = (int)h_;
                bloF.i[k] = (int)l_;
            }
            // A-frags + MFMA
#pragma unroll
            for (int ti = 0; ti < 2; ++ti) {
                int mt = 2 * a + ti;
                FragI ah, al;
                ah.v = TH4[(ks * 8 + mt) * 64 + lane];
                al.v = TL4[(ks * 8 + mt) * 64 + lane];
                MM(ah.s, bhiF.s, acc[ti]);
                MM(ah.s, bloF.s, acc[ti]);
                MM(al.s, bhiF.s, acc[ti]);
            }
        }
        __syncthreads();
    }
#undef MM
#undef LOADQ
    // epilogue: lane rows mc = mt*16 + kg*4 + reg; regs (0,1)=(Re,Im) mode mA,
    // (2,3)=mode mA+1. Split to bf16 hi/lo + negated-imag, store to SPLITX.
    const int h = hbase + ht * 16 + col;
#pragma unroll
    for (int ti = 0; ti < 2; ++ti) {
        int mt = 2 * a + ti;
        int mA = mt * 8 + kg * 2;
#pragma unroll
        for (int mi = 0; mi < 2; ++mi) {
            float xr = acc[ti][2 * mi];
            float xi = acc[ti][2 * mi + 1];
            ushort_t rh, rl, ih_, il_;
            split1(xr, rh, rl);
            split1(xi, ih_, il_);
            int m = mA + mi;
            *(ushort_t*)sx_ptr(dout, 0, m, b, h) = rh;
            *(ushort_t*)sx_ptr(dout, 1, m, b, h) = rl;
            *(ushort_t*)sx_ptr(dout, 2, m, b, h) = ih_;
            *(ushort_t*)sx_ptr(dout, 3, m, b, h) = il_;
            *(ushort_t*)sx_ptr(dout, 4, m, b, h) = (ushort_t)(ih_ ^ 0x8000);
            *(ushort_t*)sx_ptr(dout, 5, m, b, h) = (ushort_t)(il_ ^ 0x8000);
        }
    }
}

// ---------------- kernel 2: per-mode complex GEMM (unchanged round-6) ------
__global__ __launch_bounds__(512) void k_modes5(const float* __restrict__ wreal,
                                                const float* __restrict__ wimag,
                                                float* __restrict__ dout) {
    __shared__ float Wlds[2 * 32 * 16 * 18];   // 73728 B
    const int t    = threadIdx.x;
    const int wave = t >> 6;
    const int lane = t & 63;
    const int blk  = blockIdx.x;
    const int hs   = blk >> 7;           // 0..3
    const int mc   = (blk >> 5) & 3;
    const int it   = blk & 31;
    const int i0   = it * 16;
    const int m0   = mc * 16;
    const int col  = lane & 15;          // A row (i) / B col (b)
    const int kg   = lane >> 4;          // k-group
    const int hbase = hs * 128;

    const char* xp0 = sx_ptr(dout, 0, m0 + 2 * wave, col, hbase + kg * 8);

    f32x4 zero4 = {0.f, 0.f, 0.f, 0.f};
    f32x4 acc[2][2][2];                  // [mi][part][nt]
#pragma unroll
    for (int a = 0; a < 2; ++a)
#pragma unroll
        for (int bq = 0; bq < 2; ++bq)
#pragma unroll
            for (int c = 0; c < 2; ++c) acc[a][bq][c] = zero4;

    float2 st[16];                       // staging regs (double-buffer)
#define LOADK(KK)                                                             \
    {                                                                         \
        int h0_ = hbase + (KK) * 32;                                          \
        _Pragma("unroll")                                                     \
        for (int r = 0; r < 16; ++r) {                                        \
            int e = r * 512 + t;                                              \
            int m2 = e & 7, ii = (e >> 3) & 15, hh = (e >> 7) & 31;           \
            const float* src = (e >> 12) ? wimag : wreal;                     \
            st[r] = *(const float2*)&src[(size_t)(h0_ + hh) * 32768 +         \
                                         (size_t)(i0 + ii) * 64 + m0 + 2 * m2]; \
        }                                                                     \
    }

    LOADK(0);
    for (int kk = 0; kk < 4; ++kk) {
#pragma unroll
        for (int r = 0; r < 16; ++r) {
            int e = r * 512 + t;
            int m2 = e & 7, ii = (e >> 3) & 15, hh = (e >> 7) & 31;
            int part = e >> 12;
            *(float2*)&Wlds[(((part * 32 + hh) * 16) + ii) * 18 + 2 * m2] = st[r];
        }
        __syncthreads();
        if (kk < 3) LOADK(kk + 1);       // prefetch next chunk under compute
#pragma unroll
        for (int mi = 0; mi < 2; ++mi) {
            const int mloc = 2 * wave + mi;
            short8 aW[2][2];             // [part][prec]
#pragma unroll
            for (int part = 0; part < 2; ++part) {
                float v[8];
#pragma unroll
                for (int j = 0; j < 8; ++j)
                    v[j] = Wlds[((part * 32 + kg * 8 + j) * 16 + col) * 18 + mloc];
                FragI hiF, loF;
#pragma unroll
                for (int k = 0; k < 4; ++k) {
                    unsigned h, l;
                    split2(v[2 * k], v[2 * k + 1], h, l);
                    hiF.i[k] = (int)h;
                    loF.i[k] = (int)l;
                }
                aW[part][0] = hiF.s;
                aW[part][1] = loF.s;
            }
            const char* xpm = xp0 + (size_t)mi * 32768 + (size_t)kk * 2048;
#define MM(A, B, C) C = __builtin_amdgcn_mfma_f32_16x16x32_bf16(A, B, C, 0, 0, 0)
#pragma unroll
            for (int nt = 0; nt < 2; ++nt) {
                short8 bX[6];
#pragma unroll
                for (int arr = 0; arr < 6; ++arr) {
                    FragI f;
                    f.v = *(const int4*)(xpm + (size_t)arr * 4194304 +
                                         (size_t)nt * 1024);
                    bX[arr] = f.s;
                }
                MM(aW[0][0], bX[0], acc[mi][0][nt]);
                MM(aW[0][0], bX[1], acc[mi][0][nt]);
                MM(aW[0][1], bX[0], acc[mi][0][nt]);
                MM(aW[1][0], bX[4], acc[mi][0][nt]);
                MM(aW[1][0], bX[5], acc[mi][0][nt]);
                MM(aW[1][1], bX[4], acc[mi][0][nt]);
                MM(aW[0][0], bX[2], acc[mi][1][nt]);
                MM(aW[0][0], bX[3], acc[mi][1][nt]);
                MM(aW[0][1], bX[2], acc[mi][1][nt]);
                MM(aW[1][0], bX[0], acc[mi][1][nt]);
                MM(aW[1][0], bX[1], acc[mi][1][nt]);
                MM(aW[1][1], bX[0], acc[mi][1][nt]);
            }
#undef MM
        }
        __syncthreads();
    }
#undef LOADK
#pragma unroll
    for (int mi = 0; mi < 2; ++mi)
#pragma unroll
        for (int part = 0; part < 2; ++part)
#pragma unroll
            for (int nt = 0; nt < 2; ++nt) {
                int bb = nt * 16 + col;
                int c = 2 * (m0 + 2 * wave + mi) + part;
                f32x4 vv = acc[mi][part][nt];
                float4 o = make_float4(vv.x, vv.y, vv.z, vv.w);
                *(float4*)&dout[(size_t)bb * BCHUNK + (size_t)hs * 65536 +
                                (size_t)c * EQ + i0 + kg * 4] = o;
            }
}

// ---------------- kernel 3: truncated irfft via MFMA (unchanged round-6) ---
__global__ __launch_bounds__(256) void k_inv3(const unsigned* __restrict__ BFhi,
                                              const unsigned* __restrict__ BFlo,
                                              float* __restrict__ dout) {
    __shared__ unsigned Bf[4096];   // [hilo(2)][nt(2)][kb(4)][lane(64)][4] 16KB
    const int t    = threadIdx.x;
    const int wave = t >> 6;
    const int lane = t & 63;
    const int b    = blockIdx.x >> 4;
    const int it   = blockIdx.x & 15;
    const int i0   = it * 32;
    float* base = dout + (size_t)b * BCHUNK;

#pragma unroll
    for (int r = 0; r < 8; ++r) {
        int idx = r * 256 + t;               // 2048 = 64 c-pairs x 32 i
        int il = idx & 31, cp = idx >> 5;
        int c0 = 2 * cp;
        const float* p0 = base + (size_t)c0 * EQ + i0 + il;
        float s0 = p0[0] + p0[65536] + p0[2 * 65536] + p0[3 * 65536];
        const float* p1 = p0 + EQ;
        float s1 = p1[0] + p1[65536] + p1[2 * 65536] + p1[3 * 65536];
        unsigned hi, lo;
        split2(s0, s1, hi, lo);
        int nt = il >> 4, i_loc = il & 15;
        int kb = c0 >> 5, kg = (c0 & 31) >> 3, jp = (c0 & 7) >> 1;
        int u = (nt * 4 + kb) * 256 + (kg * 16 + i_loc) * 4 + jp;
        Bf[u] = hi;
        Bf[2048 + u] = lo;
    }
    __syncthreads();
    FragI bh[2][4], bl[2][4];
#pragma unroll
    for (int nt = 0; nt < 2; ++nt)
#pragma unroll
        for (int kb = 0; kb < 4; ++kb) {
            bh[nt][kb].v = *(const int4*)&Bf[(nt * 4 + kb) * 256 + lane * 4];
            bl[nt][kb].v = *(const int4*)&Bf[2048 + (nt * 4 + kb) * 256 + lane * 4];
        }
#define MM(A, B, C) C = __builtin_amdgcn_mfma_f32_16x16x32_bf16(A, B, C, 0, 0, 0)
    for (int r = 0; r < 16; ++r) {
        int lt = wave + 4 * r;
        FragI ah[4], al[4];
#pragma unroll
        for (int kb = 0; kb < 4; ++kb) {
            ah[kb].v = *(const int4*)&BFhi[lt * 1024 + kb * 256 + lane * 4];
            al[kb].v = *(const int4*)&BFlo[lt * 1024 + kb * 256 + lane * 4];
        }
        f32x4 a0 = {0.f, 0.f, 0.f, 0.f}, a1 = {0.f, 0.f, 0.f, 0.f};
#pragma unroll
        for (int kb = 0; kb < 4; ++kb) {
            MM(ah[kb].s, bh[0][kb].s, a0);
            MM(ah[kb].s, bl[0][kb].s, a0);
            MM(al[kb].s, bh[0][kb].s, a0);
            MM(ah[kb].s, bh[1][kb].s, a1);
            MM(ah[kb].s, bl[1][kb].s, a1);
            MM(al[kb].s, bh[1][kb].s, a1);
        }
        int lrow = lt * 16 + (lane >> 4) * 4;
        int icol = i0 + (lane & 15);
#pragma unroll
        for (int j = 0; j < 4; ++j) {
            base[(size_t)(lrow + j) * EQ + icol]      = a0[j];
            base[(size_t)(lrow + j) * EQ + icol + 16] = a1[j];
        }
    }
#undef MM
}

extern "C" void kernel_launch(void* const* d_in, const int* in_sizes, int n_in,
                              void* d_out, int out_size, void* d_ws, size_t ws_size,
                              hipStream_t stream) {
    const float* q  = (const float*)d_in[0];
    const float* wr = (const float*)d_in[1];
    const float* wi = (const float*)d_in[2];
    float* out = (float*)d_out;
    unsigned* BFhi = (unsigned*)d_ws;           // u32 [0, 65536)
    unsigned* BFlo = BFhi + 65536;              // u32 [65536, 131072)  (512 KB ws)

    hipLaunchKernelGGL(k_trig,   dim3(256), dim3(256), 0, stream, BFhi, BFlo, out);
    hipLaunchKernelGGL(k_dft3,   dim3(512), dim3(512), 0, stream, q, out);
    hipLaunchKernelGGL(k_modes5, dim3(512), dim3(512), 0, stream, wr, wi, out);
    hipLaunchKernelGGL(k_inv3,   dim3(512), dim3(256), 0, stream, BFhi, BFlo, out);
}